// Round 8
// baseline (602.493 us; speedup 1.0000x reference)
//
#include <hip/hip_runtime.h>

// DecoderCell v8: v6 base (simple 2-barrier loop, both-sides XOR swizzle,
// 0 bank conflicts) with 128x256 tiles (512 thr, 48KB LDS, 2-3 blocks/CU)
// for the 4 big GEMMs -> 2x compute per staged byte, half the A re-reads.
// co/factor stay on the v6 128x128 kernel. Epilogues run in two 128-col
// halves to fit LDS.
//
// h_0 layout: [gen 0:512 | con 512:768 | mean 768:832 | std 832:896 | gi 896:960 | factor 960:1088]
// A_con[32768][640] = [input 256 | factor 128 | h_con->hnew_con 256]  (swizzled)
// A_gen[32768][576] = [gi 64 | h_gen->hnew_gen 512]                   (swizzled)

typedef short  s16x8 __attribute__((ext_vector_type(8)));
typedef float  f32x4 __attribute__((ext_vector_type(4)));
typedef unsigned short ush;

#define OUTP 1088
#define NROW 32768

__device__ __forceinline__ int swz(int k, int row) {
  return (k & ~63) | ((k & 63) ^ ((row & 7) << 3));
}
__device__ __forceinline__ ush f2bf(float f) {
  union { float f; unsigned int u; } v; v.f = f;
  unsigned int u = v.u;
  return (ush)((u + 0x7FFFu + ((u >> 16) & 1u)) >> 16);  // RNE
}
__device__ __forceinline__ float bf2f(ush b) {
  union { unsigned int u; float f; } v; v.u = ((unsigned int)b) << 16;
  return v.f;
}
__device__ __forceinline__ float sigm(float x) { return 1.f / (1.f + __expf(-x)); }
__device__ __forceinline__ float tanh_(float x) { return 2.f / (1.f + __expf(-2.f * x)) - 1.f; }

__device__ __forceinline__ f32x4 mfma16(s16x8 a, s16x8 b, f32x4 c) {
  return __builtin_amdgcn_mfma_f32_16x16x32_bf16(a, b, c, 0, 0, 0);
}
__device__ __forceinline__ s16x8 ldb8(const ush* p) {
  return *reinterpret_cast<const s16x8*>(p);
}
__device__ __forceinline__ void gld16(const ush* g, ush* l) {
  __builtin_amdgcn_global_load_lds(
      (const __attribute__((address_space(1))) unsigned int*)g,
      (__attribute__((address_space(3))) unsigned int*)l, 16, 0, 0);
}
__device__ __forceinline__ ushort4 pack4(float4 a) {
  ushort4 o; o.x = f2bf(a.x); o.y = f2bf(a.y); o.z = f2bf(a.z); o.w = f2bf(a.w);
  return o;
}

// ---- prep: A_con = [input|factor|h_con] + A_gen h-section, bf16 swizzled ---
__global__ void prepA_kernel(const float* __restrict__ in, const float* __restrict__ h0,
                             ush* __restrict__ Acon, ush* __restrict__ Agen) {
  int t = blockIdx.x * 256 + threadIdx.x;      // 32768 * 144
  int row = t / 144, c = t % 144;
  if (c < 80) {
    int c8 = c * 8;
    const float* src;
    if (c8 < 256)      src = &in[(size_t)row * 256 + c8];
    else if (c8 < 384) src = &h0[(size_t)row * OUTP + 960 + (c8 - 256)];
    else               src = &h0[(size_t)row * OUTP + 512 + (c8 - 384)];
    float4 a = *reinterpret_cast<const float4*>(src);
    float4 b = *reinterpret_cast<const float4*>(src + 4);
    ushort4* d = reinterpret_cast<ushort4*>(&Acon[(size_t)row * 640 + swz(c8, row)]);
    d[0] = pack4(a); d[1] = pack4(b);
  } else {
    int c8 = (c - 80) * 8;
    float4 a = *reinterpret_cast<const float4*>(&h0[(size_t)row * OUTP + c8]);
    float4 b = *reinterpret_cast<const float4*>(&h0[(size_t)row * OUTP + c8 + 4]);
    ushort4* d = reinterpret_cast<ushort4*>(&Agen[(size_t)row * 576 + swz(64 + c8, row)]);
    d[0] = pack4(a); d[1] = pack4(b);
  }
}

// ---- prep: con weights -> [Wih(384)|Whh(256)], swizzled --------------------
__global__ void packBcon_kernel(const float* __restrict__ wih, const float* __restrict__ whh,
                                ush* __restrict__ B1, ush* __restrict__ B2) {
  int r = blockIdx.x;          // 0..767
  int c4 = threadIdx.x * 4;    // 0..636
  float4 v = (c4 < 384) ? *reinterpret_cast<const float4*>(&wih[(size_t)r * 384 + c4])
                        : *reinterpret_cast<const float4*>(&whh[(size_t)r * 256 + (c4 - 384)]);
  int pc = swz(c4, r);
  ush* dst = (r < 512) ? &B1[(size_t)r * 640 + pc] : &B2[(size_t)(r - 512) * 640 + pc];
  *reinterpret_cast<ushort4*>(dst) = pack4(v);
}

// ---- prep: gen weights -> [Wih(64)|Whh(512)], swizzled ---------------------
__global__ void packBgen_kernel(const float* __restrict__ wih, const float* __restrict__ whh,
                                ush* __restrict__ B1, ush* __restrict__ B2) {
  int r = blockIdx.x;          // 0..1535
  int c4 = threadIdx.x * 4;    // 0..572
  float4 v = (c4 < 64) ? *reinterpret_cast<const float4*>(&wih[(size_t)r * 64 + c4])
                       : *reinterpret_cast<const float4*>(&whh[(size_t)r * 512 + (c4 - 64)]);
  int pc = swz(c4, r);
  ush* dst = (r < 1024) ? &B1[(size_t)r * 576 + pc] : &B2[(size_t)(r - 1024) * 576 + pc];
  *reinterpret_cast<ushort4*>(dst) = pack4(v);
}

// ---- prep: co_W f32->bf16, swizzled (128x256) ------------------------------
__global__ void cvtco_kernel(const float* __restrict__ src, ush* __restrict__ dst) {
  int i = blockIdx.x * 256 + threadIdx.x;      // 128*64
  int row = i >> 6, c4 = (i & 63) * 4;
  float4 v = *reinterpret_cast<const float4*>(&src[(size_t)row * 256 + c4]);
  *reinterpret_cast<ushort4*>(&dst[(size_t)row * 256 + swz(c4, row)]) = pack4(v);
}

// ---- prep: row-L2-normalize fac_W (128x512) -> bf16, swizzled --------------
__global__ void facnorm_kernel(const float* __restrict__ w, ush* __restrict__ dst) {
  int row = blockIdx.x;       // 128
  int lane = threadIdx.x;     // 64
  float v[8]; float s = 0.f;
  #pragma unroll
  for (int i = 0; i < 8; ++i) { v[i] = w[row * 512 + lane * 8 + i]; s += v[i] * v[i]; }
  #pragma unroll
  for (int off = 32; off; off >>= 1) s += __shfl_xor(s, off);
  float scale = 1.f / fmaxf(sqrtf(s), 1e-12f);
  int pc = swz(lane * 8, row);
  #pragma unroll
  for (int i = 0; i < 8; ++i) dst[row * 512 + pc + i] = f2bf(v[i] * scale);
}

// ---- rsample: gi = mean + std*eps -> out + A_gen (swizzled) ----------------
__global__ void rsample_kernel(const float* __restrict__ eps, float* __restrict__ out,
                               ush* __restrict__ Agen) {
  int t = blockIdx.x * 256 + threadIdx.x;      // 32768*64
  int m = t >> 6, j = t & 63;
  float mean = out[(size_t)m * OUTP + 768 + j];
  float sd   = out[(size_t)m * OUTP + 832 + j];
  float g = mean + sd * eps[(size_t)m * 64 + j];
  out[(size_t)m * OUTP + 896 + j] = g;
  Agen[(size_t)m * 576 + (j ^ ((m & 7) << 3))] = f2bf(g);
}

// ---- WIDE GEMM: 128x256 tile, BK=64, 512 thr / 8 waves (2M x 4N) -----------
// EPI: 0 = zr-gate (z->st1 linear, rh->st2 swz), 1 = n-gate (h_new -> st1 swz
//      + out f32 coalesced). Epilogue in two 128-col halves.
template<int EPI, int KTOT, int KA1, int SA1, int SA2, int SB,
         int NT, int NHALF, int SAH, int OOFS, int SHN>
__global__ __launch_bounds__(512, 2) void gemmW_kernel(
    const ush* __restrict__ A1, const ush* __restrict__ A2,
    const ush* __restrict__ B,
    const float* __restrict__ bih, const float* __restrict__ bhh,
    const ush* __restrict__ Ah,
    const ush* __restrict__ zbuf,
    ush* __restrict__ st1, ush* __restrict__ st2,
    float* __restrict__ out)
{
  __shared__ __align__(16) ush S[(128 + 256) * 64];   // As 16KB | Bs 32KB
  const int nwg = gridDim.x;
  const int wg = (blockIdx.x & 7) * (nwg >> 3) + (blockIdx.x >> 3);  // XCD-chunked
  const int mt = wg / NT, nt = wg % NT;
  const int m0 = mt * 128, n0 = nt * 256;
  const int tid = threadIdx.x;
  const int wv = tid >> 6, lane = tid & 63;
  const int ln = lane & 15, lk = lane >> 4;
  const int wm = wv >> 2, wn = wv & 3;
  const int srow = lane >> 3;
  const int scol = (lane & 7) * 8;
  const int xs = (ln & 7) << 3;
  const int NK = KTOT / 64;

  f32x4 acc[4][4] = {};
  ush* As = S;
  ush* Bs = S + 8192;

  for (int ks = 0; ks < NK; ++ks) {
    const int k0 = ks * 64;
    const ush* Ab; size_t sa; int kk;
    if (KA1 >= KTOT || k0 < KA1) { Ab = A1; sa = SA1; kk = k0; }
    else                         { Ab = A2; sa = SA2; kk = k0 - KA1; }
    #pragma unroll
    for (int l = 0; l < 2; ++l) {
      int r0 = l * 64 + wv * 8;
      gld16(Ab + (size_t)(m0 + r0 + srow) * sa + kk + scol, &As[r0 * 64]);
    }
    #pragma unroll
    for (int l = 0; l < 4; ++l) {
      int r0 = l * 64 + wv * 8;
      gld16(B + (size_t)(n0 + r0 + srow) * SB + k0 + scol, &Bs[r0 * 64]);
    }
    asm volatile("s_waitcnt vmcnt(0)" ::: "memory");
    __syncthreads();
    #pragma unroll
    for (int kk2 = 0; kk2 < 2; ++kk2) {
      const int kb = (kk2 * 32 + lk * 8) ^ xs;
      s16x8 af[4], bf[4];
      #pragma unroll
      for (int i = 0; i < 4; ++i) af[i] = ldb8(&As[(wm * 64 + i * 16 + ln) * 64 + kb]);
      #pragma unroll
      for (int i = 0; i < 4; ++i) bf[i] = ldb8(&Bs[(wn * 64 + i * 16 + ln) * 64 + kb]);
      #pragma unroll
      for (int i = 0; i < 4; ++i)
        #pragma unroll
        for (int j = 0; j < 4; ++j)
          acc[i][j] = mfma16(af[i], bf[j], acc[i][j]);
    }
    __syncthreads();
  }

  // ---- epilogue: two 128-col halves through a 128x128 bf16 LDS tile --------
  ush* Ls = S;   // 32 KB

  #pragma unroll
  for (int jh = 0; jh < 2; ++jh) {
    const int nb = n0 + jh * 128;
    const bool isz = (EPI == 0) && (nb < NHALF);
    if ((wn >> 1) == jh) {
      #pragma unroll
      for (int i = 0; i < 4; ++i) {
        #pragma unroll
        for (int j = 0; j < 4; ++j) {
          const int jl = (wn & 1) * 64 + j * 16 + ln;   // 0..127
          const int jg = nb + jl;
          #pragma unroll
          for (int r = 0; r < 4; ++r) {
            const int rl = wm * 64 + i * 16 + lk * 4 + r;
            float val;
            if constexpr (EPI == 0) {
              const float bb = bih[jg] + bhh[jg];
              float sv = sigm(acc[i][j][r] + bb);
              if (!isz) sv *= bf2f(Ah[(size_t)(m0 + rl) * SAH + swz(jg - NHALF, rl)]);
              val = sv;
            } else {
              const float bb = bih[2 * NHALF + jg] + bhh[2 * NHALF + jg];
              const size_t m = (size_t)(m0 + rl);
              float n = tanh_(acc[i][j][r] + bb);
              float z = bf2f(zbuf[m * NHALF + jg]);
              float h = bf2f(Ah[m * SAH + swz(jg, rl)]);
              val = fminf(fmaxf(z * h + (1.f - z) * n, -5.f), 5.f);
            }
            Ls[rl * 128 + (jl ^ ((rl & 7) << 3))] = f2bf(val);
          }
        }
      }
    }
    __syncthreads();
    #pragma unroll
    for (int q = 0; q < 4; ++q) {
      int idx = q * 512 + tid;
      int rr = idx >> 4, c8 = (idx & 15) * 8;
      union { float4 f; ush u[8]; } U;
      U.f = *reinterpret_cast<const float4*>(&Ls[rr * 128 + (c8 ^ ((rr & 7) << 3))]);
      if constexpr (EPI == 0) {
        if (isz) *reinterpret_cast<float4*>(&st1[(size_t)(m0 + rr) * NHALF + nb + c8]) = U.f;
        else     *reinterpret_cast<float4*>(&st2[(size_t)(m0 + rr) * NHALF +
                                                 swz(nb - NHALF + c8, rr)]) = U.f;
      } else {
        *reinterpret_cast<float4*>(&st1[(size_t)(m0 + rr) * SHN + swz(nb + c8, rr)]) = U.f;
        float4 o0 = { bf2f(U.u[0]), bf2f(U.u[1]), bf2f(U.u[2]), bf2f(U.u[3]) };
        float4 o1 = { bf2f(U.u[4]), bf2f(U.u[5]), bf2f(U.u[6]), bf2f(U.u[7]) };
        float* ob = &out[(size_t)(m0 + rr) * OUTP + OOFS + nb + c8];
        *reinterpret_cast<float4*>(ob) = o0;
        *reinterpret_cast<float4*>(ob + 4) = o1;
      }
    }
    __syncthreads();
  }
}

// ---- NARROW GEMM (v6): 128x128 tile, 256 thr / 4 waves; EPI 2=co, 3=factor -
template<int EPI, int KTOT, int KA1, int SA1, int SA2, int SB,
         int NT, int NHALF, int SAH, int OOFS, int SHN>
__global__ __launch_bounds__(256, 4) void gemm_kernel(
    const ush* __restrict__ A1, const ush* __restrict__ A2,
    const ush* __restrict__ B,
    const float* __restrict__ bih, const float* __restrict__ bhh,
    const ush* __restrict__ Ah,
    const ush* __restrict__ zbuf,
    ush* __restrict__ st1, ush* __restrict__ st2,
    float* __restrict__ out)
{
  __shared__ ush S[2 * 128 * 64];   // As | Bs (32 KB)
  const int nwg = gridDim.x;
  const int wg = (blockIdx.x & 7) * (nwg >> 3) + (blockIdx.x >> 3);
  const int mt = wg / NT, nt = wg % NT;
  const int m0 = mt * 128, n0 = nt * 128;
  const int tid = threadIdx.x;
  const int w = tid >> 6, lane = tid & 63;
  const int ln = lane & 15, lk = lane >> 4;
  const int wm = w >> 1, wn = w & 1;
  const int srow = lane >> 3;
  const int scol = (lane & 7) * 8;
  const int NK = KTOT / 64;
  const int xs = (ln & 7) << 3;

  f32x4 acc[4][4] = {};
  ush* As = S;
  ush* Bs = S + 8192;

  for (int ks = 0; ks < NK; ++ks) {
    const int k0 = ks * 64;
    const ush* Ab; size_t sa; int kk;
    if (KA1 >= KTOT || k0 < KA1) { Ab = A1; sa = SA1; kk = k0; }
    else                         { Ab = A2; sa = SA2; kk = k0 - KA1; }
    #pragma unroll
    for (int p = 0; p < 4; ++p) {
      int r0 = p * 32 + w * 8;
      gld16(Ab + (size_t)(m0 + r0 + srow) * sa + kk + scol, &As[r0 * 64]);
    }
    #pragma unroll
    for (int p = 0; p < 4; ++p) {
      int r0 = p * 32 + w * 8;
      gld16(B + (size_t)(n0 + r0 + srow) * SB + k0 + scol, &Bs[r0 * 64]);
    }
    asm volatile("s_waitcnt vmcnt(0)" ::: "memory");
    __syncthreads();
    #pragma unroll
    for (int kk2 = 0; kk2 < 2; ++kk2) {
      const int kb = (kk2 * 32 + lk * 8) ^ xs;
      s16x8 af[4], bf[4];
      #pragma unroll
      for (int i = 0; i < 4; ++i) af[i] = ldb8(&As[(wm * 64 + i * 16 + ln) * 64 + kb]);
      #pragma unroll
      for (int i = 0; i < 4; ++i) bf[i] = ldb8(&Bs[(wn * 64 + i * 16 + ln) * 64 + kb]);
      #pragma unroll
      for (int i = 0; i < 4; ++i)
        #pragma unroll
        for (int j = 0; j < 4; ++j)
          acc[i][j] = mfma16(af[i], bf[j], acc[i][j]);
    }
    __syncthreads();
  }

  if constexpr (EPI == 2) {   // co: mean | logvar->std
    #pragma unroll
    for (int i = 0; i < 4; ++i) {
      #pragma unroll
      for (int j = 0; j < 4; ++j) {
        const int jg = n0 + wn * 64 + j * 16 + ln;
        const float bb = bih[jg];
        #pragma unroll
        for (int r = 0; r < 4; ++r) {
          const size_t m = (size_t)(m0 + wm * 64 + i * 16 + lk * 4 + r);
          float v = acc[i][j][r] + bb;
          if (jg < 64) out[m * OUTP + 768 + jg] = v;
          else         out[m * OUTP + 832 + (jg - 64)] = __expf(0.5f * v);
        }
      }
    }
  } else {                    // factor
    #pragma unroll
    for (int i = 0; i < 4; ++i)
      #pragma unroll
      for (int j = 0; j < 4; ++j) {
        const int jg = n0 + wn * 64 + j * 16 + ln;
        #pragma unroll
        for (int r = 0; r < 4; ++r)
          out[(size_t)(m0 + wm * 64 + i * 16 + lk * 4 + r) * OUTP + 960 + jg] =
              acc[i][j][r];
      }
  }
}

extern "C" void kernel_launch(void* const* d_in, const int* in_sizes, int n_in,
                              void* d_out, int out_size, void* d_ws, size_t ws_size,
                              hipStream_t stream) {
  const float* input   = (const float*)d_in[0];
  const float* h0      = (const float*)d_in[1];
  const float* eps     = (const float*)d_in[2];
  const float* gen_Wih = (const float*)d_in[3];
  const float* gen_bih = (const float*)d_in[4];
  const float* gen_Whh = (const float*)d_in[5];
  const float* gen_bhh = (const float*)d_in[6];
  const float* con_Wih = (const float*)d_in[7];
  const float* con_bih = (const float*)d_in[8];
  const float* con_Whh = (const float*)d_in[9];
  const float* con_bhh = (const float*)d_in[10];
  const float* fac_W   = (const float*)d_in[11];
  const float* co_W    = (const float*)d_in[12];
  const float* co_b    = (const float*)d_in[13];
  float* out = (float*)d_out;

  ush* ws = (ush*)d_ws;
  ush* A_gen  = ws;                                  // 32768*576
  ush* A_con  = A_gen + (size_t)NROW * 576;          // 32768*640
  ush* z_con  = A_con + (size_t)NROW * 640;          // 32768*256
  ush* rh_con = z_con + (size_t)NROW * 256;          // 32768*256
  ush* B1c    = rh_con + (size_t)NROW * 256;         // 512*640
  ush* B2c    = B1c + 512 * 640;                     // 256*640
  ush* B1g    = B2c + 256 * 640;                     // 1024*576
  ush* B2g    = B1g + 1024 * 576;                    // 512*576
  ush* coWb   = B2g + 512 * 576;                     // 128*256
  ush* facWn  = coWb + 128 * 256;                    // 128*512
  // aliases over dead con-phase buffers (gen phase runs after co/rsample):
  ush* z_gen  = A_con;                               // 32768*512 <= A_con
  ush* rh_gen = z_con;                               // 32768*512 == z_con+rh_con

  // ---- prep ----
  packBcon_kernel<<<768, 160, 0, stream>>>(con_Wih, con_Whh, B1c, B2c);
  packBgen_kernel<<<1536, 144, 0, stream>>>(gen_Wih, gen_Whh, B1g, B2g);
  cvtco_kernel<<<32, 256, 0, stream>>>(co_W, coWb);
  facnorm_kernel<<<128, 64, 0, stream>>>(fac_W, facWn);
  prepA_kernel<<<18432, 256, 0, stream>>>(input, h0, A_con, A_gen);

  // ---- controller: z,r -> rh ; n -> h_new ; co ; rsample ----
  gemmW_kernel<0, 640, 640, 640, 640, 640, 2, 256, 640, 0, 0>
      <<<512, 512, 0, stream>>>(A_con, A_con, B1c, con_bih, con_bhh,
                                A_con + 384, nullptr, z_con, rh_con, out);
  gemmW_kernel<1, 640, 384, 640, 256, 640, 1, 256, 640, 512, 640>
      <<<256, 512, 0, stream>>>(A_con, rh_con, B2c, con_bih, con_bhh,
                                A_con + 384, z_con, A_con + 384, nullptr, out);
  gemm_kernel<2, 256, 256, 640, 640, 256, 1, 64, 640, 0, 0>
      <<<256, 256, 0, stream>>>(A_con + 384, A_con + 384, coWb, co_b, co_b,
                                nullptr, nullptr, nullptr, nullptr, out);
  rsample_kernel<<<8192, 256, 0, stream>>>(eps, out, A_gen);

  // ---- generator: z,r -> rh ; n -> h_new ; factor ----
  gemmW_kernel<0, 576, 576, 576, 576, 576, 4, 512, 576, 0, 0>
      <<<1024, 512, 0, stream>>>(A_gen, A_gen, B1g, gen_bih, gen_bhh,
                                 A_gen + 64, nullptr, z_gen, rh_gen, out);
  gemmW_kernel<1, 576, 64, 576, 512, 576, 2, 512, 576, 0, 576>
      <<<512, 512, 0, stream>>>(A_gen, rh_gen, B2g, gen_bih, gen_bhh,
                                A_gen + 64, z_gen, A_gen + 64, nullptr, out);
  gemm_kernel<3, 512, 512, 576, 576, 512, 1, 0, 576, 960, 0>
      <<<256, 256, 0, stream>>>(A_gen + 64, A_gen + 64, facWn, gen_bih, gen_bhh,
                                nullptr, nullptr, nullptr, nullptr, out);
}

// Round 9
// 291.400 us; speedup vs baseline: 2.0676x; 2.0676x over previous
//
#include <hip/hip_runtime.h>

// DecoderCell v9: v6 base + the untested combination for the 4 big GEMMs:
// double-buffered BK=64 with counted vmcnt(4) (stage issued one K-step ahead
// -> ~zero drain), both-sides XOR swizzle (0 conflicts), 512 thr / 8 waves,
// 64KB LDS -> 2 blocks/CU = 16 waves/CU (same TLP as v6), raw s_barrier,
// no sched pins, setprio around MFMA. co/factor keep the v6 narrow kernel.
//
// h_0 layout: [gen 0:512 | con 512:768 | mean 768:832 | std 832:896 | gi 896:960 | factor 960:1088]
// A_con[32768][640] = [input 256 | factor 128 | h_con->hnew_con 256]  (swizzled)
// A_gen[32768][576] = [gi 64 | h_gen->hnew_gen 512]                   (swizzled)

typedef short  s16x8 __attribute__((ext_vector_type(8)));
typedef float  f32x4 __attribute__((ext_vector_type(4)));
typedef unsigned short ush;

#define OUTP 1088
#define NROW 32768

__device__ __forceinline__ int swz(int k, int row) {
  return (k & ~63) | ((k & 63) ^ ((row & 7) << 3));
}
__device__ __forceinline__ ush f2bf(float f) {
  union { float f; unsigned int u; } v; v.f = f;
  unsigned int u = v.u;
  return (ush)((u + 0x7FFFu + ((u >> 16) & 1u)) >> 16);  // RNE
}
__device__ __forceinline__ float bf2f(ush b) {
  union { unsigned int u; float f; } v; v.u = ((unsigned int)b) << 16;
  return v.f;
}
__device__ __forceinline__ float sigm(float x) { return 1.f / (1.f + __expf(-x)); }
__device__ __forceinline__ float tanh_(float x) { return 2.f / (1.f + __expf(-2.f * x)) - 1.f; }

__device__ __forceinline__ f32x4 mfma16(s16x8 a, s16x8 b, f32x4 c) {
  return __builtin_amdgcn_mfma_f32_16x16x32_bf16(a, b, c, 0, 0, 0);
}
__device__ __forceinline__ s16x8 ldb8(const ush* p) {
  return *reinterpret_cast<const s16x8*>(p);
}
__device__ __forceinline__ void gld16(const ush* g, ush* l) {
  __builtin_amdgcn_global_load_lds(
      (const __attribute__((address_space(1))) unsigned int*)g,
      (__attribute__((address_space(3))) unsigned int*)l, 16, 0, 0);
}
__device__ __forceinline__ ushort4 pack4(float4 a) {
  ushort4 o; o.x = f2bf(a.x); o.y = f2bf(a.y); o.z = f2bf(a.z); o.w = f2bf(a.w);
  return o;
}

// ---- prep: A_con = [input|factor|h_con] + A_gen h-section, bf16 swizzled ---
__global__ void prepA_kernel(const float* __restrict__ in, const float* __restrict__ h0,
                             ush* __restrict__ Acon, ush* __restrict__ Agen) {
  int t = blockIdx.x * 256 + threadIdx.x;      // 32768 * 144
  int row = t / 144, c = t % 144;
  if (c < 80) {
    int c8 = c * 8;
    const float* src;
    if (c8 < 256)      src = &in[(size_t)row * 256 + c8];
    else if (c8 < 384) src = &h0[(size_t)row * OUTP + 960 + (c8 - 256)];
    else               src = &h0[(size_t)row * OUTP + 512 + (c8 - 384)];
    float4 a = *reinterpret_cast<const float4*>(src);
    float4 b = *reinterpret_cast<const float4*>(src + 4);
    ushort4* d = reinterpret_cast<ushort4*>(&Acon[(size_t)row * 640 + swz(c8, row)]);
    d[0] = pack4(a); d[1] = pack4(b);
  } else {
    int c8 = (c - 80) * 8;
    float4 a = *reinterpret_cast<const float4*>(&h0[(size_t)row * OUTP + c8]);
    float4 b = *reinterpret_cast<const float4*>(&h0[(size_t)row * OUTP + c8 + 4]);
    ushort4* d = reinterpret_cast<ushort4*>(&Agen[(size_t)row * 576 + swz(64 + c8, row)]);
    d[0] = pack4(a); d[1] = pack4(b);
  }
}

// ---- prep: con weights -> [Wih(384)|Whh(256)], swizzled --------------------
__global__ void packBcon_kernel(const float* __restrict__ wih, const float* __restrict__ whh,
                                ush* __restrict__ B1, ush* __restrict__ B2) {
  int r = blockIdx.x;          // 0..767
  int c4 = threadIdx.x * 4;    // 0..636
  float4 v = (c4 < 384) ? *reinterpret_cast<const float4*>(&wih[(size_t)r * 384 + c4])
                        : *reinterpret_cast<const float4*>(&whh[(size_t)r * 256 + (c4 - 384)]);
  int pc = swz(c4, r);
  ush* dst = (r < 512) ? &B1[(size_t)r * 640 + pc] : &B2[(size_t)(r - 512) * 640 + pc];
  *reinterpret_cast<ushort4*>(dst) = pack4(v);
}

// ---- prep: gen weights -> [Wih(64)|Whh(512)], swizzled ---------------------
__global__ void packBgen_kernel(const float* __restrict__ wih, const float* __restrict__ whh,
                                ush* __restrict__ B1, ush* __restrict__ B2) {
  int r = blockIdx.x;          // 0..1535
  int c4 = threadIdx.x * 4;    // 0..572
  float4 v = (c4 < 64) ? *reinterpret_cast<const float4*>(&wih[(size_t)r * 64 + c4])
                       : *reinterpret_cast<const float4*>(&whh[(size_t)r * 512 + (c4 - 64)]);
  int pc = swz(c4, r);
  ush* dst = (r < 1024) ? &B1[(size_t)r * 576 + pc] : &B2[(size_t)(r - 1024) * 576 + pc];
  *reinterpret_cast<ushort4*>(dst) = pack4(v);
}

// ---- prep: co_W f32->bf16, swizzled (128x256) ------------------------------
__global__ void cvtco_kernel(const float* __restrict__ src, ush* __restrict__ dst) {
  int i = blockIdx.x * 256 + threadIdx.x;      // 128*64
  int row = i >> 6, c4 = (i & 63) * 4;
  float4 v = *reinterpret_cast<const float4*>(&src[(size_t)row * 256 + c4]);
  *reinterpret_cast<ushort4*>(&dst[(size_t)row * 256 + swz(c4, row)]) = pack4(v);
}

// ---- prep: row-L2-normalize fac_W (128x512) -> bf16, swizzled --------------
__global__ void facnorm_kernel(const float* __restrict__ w, ush* __restrict__ dst) {
  int row = blockIdx.x;       // 128
  int lane = threadIdx.x;     // 64
  float v[8]; float s = 0.f;
  #pragma unroll
  for (int i = 0; i < 8; ++i) { v[i] = w[row * 512 + lane * 8 + i]; s += v[i] * v[i]; }
  #pragma unroll
  for (int off = 32; off; off >>= 1) s += __shfl_xor(s, off);
  float scale = 1.f / fmaxf(sqrtf(s), 1e-12f);
  int pc = swz(lane * 8, row);
  #pragma unroll
  for (int i = 0; i < 8; ++i) dst[row * 512 + pc + i] = f2bf(v[i] * scale);
}

// ---- rsample: gi = mean + std*eps -> out + A_gen (swizzled) ----------------
__global__ void rsample_kernel(const float* __restrict__ eps, float* __restrict__ out,
                               ush* __restrict__ Agen) {
  int t = blockIdx.x * 256 + threadIdx.x;      // 32768*64
  int m = t >> 6, j = t & 63;
  float mean = out[(size_t)m * OUTP + 768 + j];
  float sd   = out[(size_t)m * OUTP + 832 + j];
  float g = mean + sd * eps[(size_t)m * 64 + j];
  out[(size_t)m * OUTP + 896 + j] = g;
  Agen[(size_t)m * 576 + (j ^ ((m & 7) << 3))] = f2bf(g);
}

// ---- DBUF GEMM: 128x128 tile, BK=64, 512 thr / 8 waves (2M x 4N) -----------
// Double-buffered LDS (2x32KB), counted vmcnt(4): stage(t+1) issued before
// waiting on stage(t) -> near-zero drain. Raw s_barrier (no vmcnt(0) drain).
// EPI: 0 = zr-gate (z->st1 linear, rh->st2 swz), 1 = n-gate (h_new -> st1 swz
//      + out f32 coalesced).
template<int EPI, int KTOT, int KA1, int SA1, int SA2, int SB,
         int NT, int NHALF, int SAH, int OOFS, int SHN>
__global__ __launch_bounds__(512, 2) void gemmD_kernel(
    const ush* __restrict__ A1, const ush* __restrict__ A2,
    const ush* __restrict__ B,
    const float* __restrict__ bih, const float* __restrict__ bhh,
    const ush* __restrict__ Ah,
    const ush* __restrict__ zbuf,
    ush* __restrict__ st1, ush* __restrict__ st2,
    float* __restrict__ out)
{
  __shared__ __align__(16) ush S[2 * 2 * 128 * 64];   // [buf][A|B], 64 KB
  const int nwg = gridDim.x;
  const int wg = (blockIdx.x & 7) * (nwg >> 3) + (blockIdx.x >> 3);  // XCD-chunked
  const int mt = wg / NT, nt = wg % NT;
  const int m0 = mt * 128, n0 = nt * 128;
  const int tid = threadIdx.x;
  const int wv = tid >> 6, lane = tid & 63;
  const int ln = lane & 15, lk = lane >> 4;
  const int wm = wv >> 2, wn = wv & 3;       // 2 M-halves x 4 N-quarters
  const int srow = lane >> 3;
  const int scol = (lane & 7) * 8;
  const int xs = (ln & 7) << 3;
  const int NK = KTOT / 64;

  f32x4 acc[4][2] = {};

  auto STAGE = [&](int t, int b) {
    const int k0 = t * 64;
    ush* As = &S[b * 16384];
    ush* Bs = As + 8192;
    const ush* Ab; size_t sa; int kk;
    if (KA1 >= KTOT || k0 < KA1) { Ab = A1; sa = SA1; kk = k0; }
    else                         { Ab = A2; sa = SA2; kk = k0 - KA1; }
    #pragma unroll
    for (int l = 0; l < 2; ++l) {
      int r0 = (wv * 2 + l) * 8;
      gld16(Ab + (size_t)(m0 + r0 + srow) * sa + kk + scol, &As[r0 * 64]);
    }
    #pragma unroll
    for (int l = 0; l < 2; ++l) {
      int r0 = (wv * 2 + l) * 8;
      gld16(B + (size_t)(n0 + r0 + srow) * SB + k0 + scol, &Bs[r0 * 64]);
    }
  };

  STAGE(0, 0);
  for (int t = 0; t < NK; ++t) {
    if (t + 1 < NK) {
      STAGE(t + 1, (t + 1) & 1);
      asm volatile("s_waitcnt vmcnt(4)" ::: "memory");   // stage(t) landed
    } else {
      asm volatile("s_waitcnt vmcnt(0)" ::: "memory");
    }
    __builtin_amdgcn_s_barrier();
    const ush* As = &S[(t & 1) * 16384];
    const ush* Bs = As + 8192;
    __builtin_amdgcn_s_setprio(1);
    #pragma unroll
    for (int kk2 = 0; kk2 < 2; ++kk2) {
      const int kb = (kk2 * 32 + lk * 8) ^ xs;
      s16x8 af[4], bf[2];
      #pragma unroll
      for (int i = 0; i < 4; ++i) af[i] = ldb8(&As[(wm * 64 + i * 16 + ln) * 64 + kb]);
      #pragma unroll
      for (int j = 0; j < 2; ++j) bf[j] = ldb8(&Bs[(wn * 32 + j * 16 + ln) * 64 + kb]);
      #pragma unroll
      for (int i = 0; i < 4; ++i)
        #pragma unroll
        for (int j = 0; j < 2; ++j)
          acc[i][j] = mfma16(af[i], bf[j], acc[i][j]);
    }
    __builtin_amdgcn_s_setprio(0);
    asm volatile("s_waitcnt lgkmcnt(0)" ::: "memory");   // buf free before re-stage
    __builtin_amdgcn_s_barrier();
  }

  // ---- epilogue via 128x128 bf16 LDS tile (coalesced dumps) ----------------
  ush* Ls = S;

  if constexpr (EPI == 0) {          // z | r gates
    const bool isz = (n0 < NHALF);
    #pragma unroll
    for (int i = 0; i < 4; ++i) {
      #pragma unroll
      for (int j = 0; j < 2; ++j) {
        const int jl = wn * 32 + j * 16 + ln;
        const int jg = n0 + jl;
        const float bb = bih[jg] + bhh[jg];
        #pragma unroll
        for (int r = 0; r < 4; ++r) {
          const int rl = wm * 64 + i * 16 + lk * 4 + r;
          float sv = sigm(acc[i][j][r] + bb);
          if (!isz) sv *= bf2f(Ah[(size_t)(m0 + rl) * SAH + swz(jg - NHALF, rl)]);
          Ls[rl * 128 + (jl ^ ((rl & 7) << 3))] = f2bf(sv);
        }
      }
    }
    __syncthreads();
    #pragma unroll
    for (int q = 0; q < 4; ++q) {
      int idx = q * 512 + tid;
      int r = idx >> 4, c8 = (idx & 15) * 8;
      float4 v = *reinterpret_cast<const float4*>(&Ls[r * 128 + (c8 ^ ((r & 7) << 3))]);
      if (isz) *reinterpret_cast<float4*>(&st1[(size_t)(m0 + r) * NHALF + n0 + c8]) = v;
      else     *reinterpret_cast<float4*>(&st2[(size_t)(m0 + r) * NHALF +
                                               swz(n0 - NHALF + c8, r)]) = v;
    }
  } else {                           // n gate + combine
    #pragma unroll
    for (int i = 0; i < 4; ++i) {
      #pragma unroll
      for (int j = 0; j < 2; ++j) {
        const int jl = wn * 32 + j * 16 + ln;
        const int jg = n0 + jl;
        const float bb = bih[2 * NHALF + jg] + bhh[2 * NHALF + jg];
        #pragma unroll
        for (int r = 0; r < 4; ++r) {
          const int rl = wm * 64 + i * 16 + lk * 4 + r;
          const size_t m = (size_t)(m0 + rl);
          float n = tanh_(acc[i][j][r] + bb);
          float z = bf2f(zbuf[m * NHALF + jg]);
          float h = bf2f(Ah[m * SAH + swz(jg, rl)]);
          float hv = fminf(fmaxf(z * h + (1.f - z) * n, -5.f), 5.f);
          Ls[rl * 128 + (jl ^ ((rl & 7) << 3))] = f2bf(hv);
        }
      }
    }
    __syncthreads();
    #pragma unroll
    for (int q = 0; q < 4; ++q) {
      int idx = q * 512 + tid;
      int r = idx >> 4, c8 = (idx & 15) * 8;
      union { float4 f; ush u[8]; } U;
      U.f = *reinterpret_cast<const float4*>(&Ls[r * 128 + (c8 ^ ((r & 7) << 3))]);
      *reinterpret_cast<float4*>(&st1[(size_t)(m0 + r) * SHN + swz(n0 + c8, r)]) = U.f;
      float4 o0 = { bf2f(U.u[0]), bf2f(U.u[1]), bf2f(U.u[2]), bf2f(U.u[3]) };
      float4 o1 = { bf2f(U.u[4]), bf2f(U.u[5]), bf2f(U.u[6]), bf2f(U.u[7]) };
      float* ob = &out[(size_t)(m0 + r) * OUTP + OOFS + n0 + c8];
      *reinterpret_cast<float4*>(ob) = o0;
      *reinterpret_cast<float4*>(ob + 4) = o1;
    }
  }
}

// ---- NARROW GEMM (v6): 128x128, 256 thr, single-buf; EPI 2=co, 3=factor ----
template<int EPI, int KTOT, int KA1, int SA1, int SA2, int SB,
         int NT, int NHALF, int SAH, int OOFS, int SHN>
__global__ __launch_bounds__(256, 4) void gemm_kernel(
    const ush* __restrict__ A1, const ush* __restrict__ A2,
    const ush* __restrict__ B,
    const float* __restrict__ bih, const float* __restrict__ bhh,
    const ush* __restrict__ Ah,
    const ush* __restrict__ zbuf,
    ush* __restrict__ st1, ush* __restrict__ st2,
    float* __restrict__ out)
{
  __shared__ ush S[2 * 128 * 64];   // As | Bs (32 KB)
  const int nwg = gridDim.x;
  const int wg = (blockIdx.x & 7) * (nwg >> 3) + (blockIdx.x >> 3);
  const int mt = wg / NT, nt = wg % NT;
  const int m0 = mt * 128, n0 = nt * 128;
  const int tid = threadIdx.x;
  const int w = tid >> 6, lane = tid & 63;
  const int ln = lane & 15, lk = lane >> 4;
  const int wm = w >> 1, wn = w & 1;
  const int srow = lane >> 3;
  const int scol = (lane & 7) * 8;
  const int NK = KTOT / 64;
  const int xs = (ln & 7) << 3;

  f32x4 acc[4][4] = {};
  ush* As = S;
  ush* Bs = S + 8192;

  for (int ks = 0; ks < NK; ++ks) {
    const int k0 = ks * 64;
    const ush* Ab; size_t sa; int kk;
    if (KA1 >= KTOT || k0 < KA1) { Ab = A1; sa = SA1; kk = k0; }
    else                         { Ab = A2; sa = SA2; kk = k0 - KA1; }
    #pragma unroll
    for (int p = 0; p < 4; ++p) {
      int r0 = p * 32 + w * 8;
      gld16(Ab + (size_t)(m0 + r0 + srow) * sa + kk + scol, &As[r0 * 64]);
    }
    #pragma unroll
    for (int p = 0; p < 4; ++p) {
      int r0 = p * 32 + w * 8;
      gld16(B + (size_t)(n0 + r0 + srow) * SB + k0 + scol, &Bs[r0 * 64]);
    }
    asm volatile("s_waitcnt vmcnt(0)" ::: "memory");
    __syncthreads();
    #pragma unroll
    for (int kk2 = 0; kk2 < 2; ++kk2) {
      const int kb = (kk2 * 32 + lk * 8) ^ xs;
      s16x8 af[4], bf[4];
      #pragma unroll
      for (int i = 0; i < 4; ++i) af[i] = ldb8(&As[(wm * 64 + i * 16 + ln) * 64 + kb]);
      #pragma unroll
      for (int i = 0; i < 4; ++i) bf[i] = ldb8(&Bs[(wn * 64 + i * 16 + ln) * 64 + kb]);
      #pragma unroll
      for (int i = 0; i < 4; ++i)
        #pragma unroll
        for (int j = 0; j < 4; ++j)
          acc[i][j] = mfma16(af[i], bf[j], acc[i][j]);
    }
    __syncthreads();
  }

  if constexpr (EPI == 2) {   // co: mean | logvar->std
    #pragma unroll
    for (int i = 0; i < 4; ++i) {
      #pragma unroll
      for (int j = 0; j < 4; ++j) {
        const int jg = n0 + wn * 64 + j * 16 + ln;
        const float bb = bih[jg];
        #pragma unroll
        for (int r = 0; r < 4; ++r) {
          const size_t m = (size_t)(m0 + wm * 64 + i * 16 + lk * 4 + r);
          float v = acc[i][j][r] + bb;
          if (jg < 64) out[m * OUTP + 768 + jg] = v;
          else         out[m * OUTP + 832 + (jg - 64)] = __expf(0.5f * v);
        }
      }
    }
  } else {                    // factor
    #pragma unroll
    for (int i = 0; i < 4; ++i)
      #pragma unroll
      for (int j = 0; j < 4; ++j) {
        const int jg = n0 + wn * 64 + j * 16 + ln;
        #pragma unroll
        for (int r = 0; r < 4; ++r)
          out[(size_t)(m0 + wm * 64 + i * 16 + lk * 4 + r) * OUTP + 960 + jg] =
              acc[i][j][r];
      }
  }
}

extern "C" void kernel_launch(void* const* d_in, const int* in_sizes, int n_in,
                              void* d_out, int out_size, void* d_ws, size_t ws_size,
                              hipStream_t stream) {
  const float* input   = (const float*)d_in[0];
  const float* h0      = (const float*)d_in[1];
  const float* eps     = (const float*)d_in[2];
  const float* gen_Wih = (const float*)d_in[3];
  const float* gen_bih = (const float*)d_in[4];
  const float* gen_Whh = (const float*)d_in[5];
  const float* gen_bhh = (const float*)d_in[6];
  const float* con_Wih = (const float*)d_in[7];
  const float* con_bih = (const float*)d_in[8];
  const float* con_Whh = (const float*)d_in[9];
  const float* con_bhh = (const float*)d_in[10];
  const float* fac_W   = (const float*)d_in[11];
  const float* co_W    = (const float*)d_in[12];
  const float* co_b    = (const float*)d_in[13];
  float* out = (float*)d_out;

  ush* ws = (ush*)d_ws;
  ush* A_gen  = ws;                                  // 32768*576
  ush* A_con  = A_gen + (size_t)NROW * 576;          // 32768*640
  ush* z_con  = A_con + (size_t)NROW * 640;          // 32768*256
  ush* rh_con = z_con + (size_t)NROW * 256;          // 32768*256
  ush* B1c    = rh_con + (size_t)NROW * 256;         // 512*640
  ush* B2c    = B1c + 512 * 640;                     // 256*640
  ush* B1g    = B2c + 256 * 640;                     // 1024*576
  ush* B2g    = B1g + 1024 * 576;                    // 512*576
  ush* coWb   = B2g + 512 * 576;                     // 128*256
  ush* facWn  = coWb + 128 * 256;                    // 128*512
  // aliases over dead con-phase buffers (gen phase runs after co/rsample):
  ush* z_gen  = A_con;                               // 32768*512 <= A_con
  ush* rh_gen = z_con;                               // 32768*512 == z_con+rh_con

  // ---- prep ----
  packBcon_kernel<<<768, 160, 0, stream>>>(con_Wih, con_Whh, B1c, B2c);
  packBgen_kernel<<<1536, 144, 0, stream>>>(gen_Wih, gen_Whh, B1g, B2g);
  cvtco_kernel<<<32, 256, 0, stream>>>(co_W, coWb);
  facnorm_kernel<<<128, 64, 0, stream>>>(fac_W, facWn);
  prepA_kernel<<<18432, 256, 0, stream>>>(input, h0, A_con, A_gen);

  // ---- controller: z,r -> rh ; n -> h_new ; co ; rsample ----
  gemmD_kernel<0, 640, 640, 640, 640, 640, 4, 256, 640, 0, 0>
      <<<1024, 512, 0, stream>>>(A_con, A_con, B1c, con_bih, con_bhh,
                                 A_con + 384, nullptr, z_con, rh_con, out);
  gemmD_kernel<1, 640, 384, 640, 256, 640, 2, 256, 640, 512, 640>
      <<<512, 512, 0, stream>>>(A_con, rh_con, B2c, con_bih, con_bhh,
                                A_con + 384, z_con, A_con + 384, nullptr, out);
  gemm_kernel<2, 256, 256, 640, 640, 256, 1, 64, 640, 0, 0>
      <<<256, 256, 0, stream>>>(A_con + 384, A_con + 384, coWb, co_b, co_b,
                                nullptr, nullptr, nullptr, nullptr, out);
  rsample_kernel<<<8192, 256, 0, stream>>>(eps, out, A_gen);

  // ---- generator: z,r -> rh ; n -> h_new ; factor ----
  gemmD_kernel<0, 576, 576, 576, 576, 576, 8, 512, 576, 0, 0>
      <<<2048, 512, 0, stream>>>(A_gen, A_gen, B1g, gen_bih, gen_bhh,
                                 A_gen + 64, nullptr, z_gen, rh_gen, out);
  gemmD_kernel<1, 576, 64, 576, 512, 576, 4, 512, 576, 0, 576>
      <<<1024, 512, 0, stream>>>(A_gen, rh_gen, B2g, gen_bih, gen_bhh,
                                 A_gen + 64, z_gen, A_gen + 64, nullptr, out);
  gemm_kernel<3, 512, 512, 576, 576, 512, 1, 0, 576, 960, 0>
      <<<256, 256, 0, stream>>>(A_gen + 64, A_gen + 64, facWn, gen_bih, gen_bhh,
                                nullptr, nullptr, nullptr, nullptr, out);
}